// Round 1
// baseline (736.361 us; speedup 1.0000x reference)
//
#include <hip/hip_runtime.h>
#include <math.h>

// Problem constants
#define BB 4
#define LL 2048
#define DN 1920          // d_inner * joints
#define HJ 5             // joints
#define DI 384           // d_inner
#define RR 12            // dt_rank
#define NS 16            // n_state
#define KC 88            // K_GROUP * (R + 2N) = 2*44
#define NCH 16           // chunks
#define CH 128           // chunk length (L / NCH)

#define L2E 1.44269504088896f
#define LN2 0.69314718055995f

__device__ __forceinline__ float fast_exp2(float x) {
#if __has_builtin(__builtin_amdgcn_exp2f)
  return __builtin_amdgcn_exp2f(x);
#else
  return exp2f(x);
#endif
}
__device__ __forceinline__ float fast_log2(float x) {
#if __has_builtin(__builtin_amdgcn_logf)
  return __builtin_amdgcn_logf(x);   // v_log_f32 computes log2(x)
#else
  return log2f(x);
#endif
}
// softplus(x) = ln(1 + e^x); clamp at 20 to avoid log2(inf) and match identity tail
__device__ __forceinline__ float softplusf(float x) {
  float t = fast_exp2(x * L2E);
  float sp = LN2 * fast_log2(1.0f + t);
  return (x > 20.0f) ? x : sp;
}

// ---------------- prep: transpose x_proj_weight to [d][88], A2 = -exp(A_logs) ----
__global__ __launch_bounds__(256) void prep_kernel(
    const float* __restrict__ W,        // [2][44][1920]
    const float* __restrict__ A_logs,   // [3840][16]
    float* __restrict__ Wt,             // [1920][88]
    float* __restrict__ A2)             // [3840][16]
{
  int i = blockIdx.x * blockDim.x + threadIdx.x;
  int stride = gridDim.x * blockDim.x;
  for (int idx = i; idx < DN * KC; idx += stride) {
    int d = idx / KC;
    int j = idx - d * KC;               // j = k*44 + c
    Wt[idx] = W[j * DN + d];
  }
  for (int idx = i; idx < 2 * DN * NS; idx += stride) {
    A2[idx] = -expf(A_logs[idx]);
  }
}

// ---------------- projection: proj[b][m][kc] = sum_d xflat[b,d,m] * Wt[d][kc] ----
// grid (128, 4) block (64, 4); thread = (m-lane, quarter of 88 outputs); d split by 4.
__global__ __launch_bounds__(256) void proj_kernel(
    const float* __restrict__ x,        // [B][384][2048][5]
    const float* __restrict__ Wt,       // [1920][88]
    float* __restrict__ proj)           // [B*L][88]  (pre-zeroed)
{
  int mlane = threadIdx.x;              // 0..63
  int jq = threadIdx.y;                 // 0..3  -> 22 outputs
  int mg = blockIdx.x * 64 + mlane;     // 0..8191
  int ds = blockIdx.y;                  // 0..3  -> 480 d's
  int b = mg >> 11;
  int m = mg & (LL - 1);
  float acc[22];
#pragma unroll
  for (int j = 0; j < 22; ++j) acc[j] = 0.0f;
  const float* xb = x + (size_t)b * DI * LL * HJ;
  int d0 = ds * 480;
  for (int dd = 0; dd < 480; ++dd) {
    int d = d0 + dd;
    int c = d / HJ;
    int h2 = d - c * HJ;
    float xv = xb[(c * LL + m) * HJ + h2];
    const float* w = Wt + d * KC + jq * 22;   // wave-uniform -> s_load
#pragma unroll
    for (int j = 0; j < 22; ++j) acc[j] = fmaf(w[j], xv, acc[j]);
  }
  float* pr = proj + (size_t)mg * KC + jq * 22;
#pragma unroll
  for (int j = 0; j < 22; ++j) atomicAdd(pr + j, acc[j]);
}

// ---------------- pass A: per-chunk h_end (from h0=0) and S = sum(delta) --------
__global__ __launch_bounds__(64) void scan_passA(
    const float* __restrict__ x,
    const float* __restrict__ proj,     // [B*L][88]
    const float* __restrict__ dtw_g,    // [2][1920][12]
    const float* __restrict__ dtb_g,    // [2][1920]
    const float* __restrict__ A2,       // [2*1920][16]
    float* __restrict__ hend,           // [8][16][1920][16]
    float* __restrict__ Sout)           // [8][16][1920]
{
  int lane = threadIdx.x;
  int d = blockIdx.x * 64 + lane;
  int bk = blockIdx.y;
  int b = bk >> 1, k = bk & 1;
  int ch = blockIdx.z;
  int kd = k * DN + d;

  float a[NS], w[RR];
  const float* ap = A2 + kd * NS;
#pragma unroll
  for (int n = 0; n < NS; ++n) a[n] = ap[n];
  const float* wp = dtw_g + kd * RR;
#pragma unroll
  for (int r = 0; r < RR; ++r) w[r] = wp[r];
  float bias = dtb_g[kd];

  int c = d / HJ, hh = d - c * HJ;
  const float* ub = x + (size_t)(b * DI + c) * LL * HJ + hh;

  float h[NS];
#pragma unroll
  for (int n = 0; n < NS; ++n) h[n] = 0.0f;
  float S = 0.0f;

  int s0 = ch * CH;
  for (int s = s0; s < s0 + CH; ++s) {
    int m = k ? (LL - 1 - s) : s;
    const float* pp = proj + (size_t)(b * LL + m) * KC + k * 44;  // uniform -> s_load
    float dr = bias;
#pragma unroll
    for (int r = 0; r < RR; ++r) dr = fmaf(pp[r], w[r], dr);
    float delta = softplusf(dr);
    float u = ub[m * HJ];
    float du = delta * u;
    float dl2 = delta * L2E;
#pragma unroll
    for (int n = 0; n < NS; ++n) {
      float dA = fast_exp2(dl2 * a[n]);
      h[n] = fmaf(dA, h[n], du * pp[12 + n]);
    }
    S += delta;
  }
  float* hb = hend + ((size_t)(bk * NCH + ch) * DN + d) * NS;
#pragma unroll
  for (int n = 0; n < NS; ++n) hb[n] = h[n];
  Sout[(bk * NCH + ch) * DN + d] = S;
}

// ---------------- pass B: sequential chunk combine; hbuf becomes h_init ---------
__global__ __launch_bounds__(256) void scan_passB(
    const float* __restrict__ A2,
    float* __restrict__ hbuf,           // in: h_end, out: h_init
    const float* __restrict__ Sbuf)
{
  int idx = blockIdx.x * 256 + threadIdx.x;   // 0..15359
  if (idx >= 8 * DN) return;
  int bk = idx / DN, d = idx - bk * DN;
  int k = bk & 1;
  const float* ap = A2 + (k * DN + d) * NS;
  float a[NS];
#pragma unroll
  for (int n = 0; n < NS; ++n) a[n] = ap[n];
  float h[NS];
#pragma unroll
  for (int n = 0; n < NS; ++n) h[n] = 0.0f;
  for (int ch = 0; ch < NCH; ++ch) {
    float* hb = hbuf + ((size_t)(bk * NCH + ch) * DN + d) * NS;
    float he[NS];
#pragma unroll
    for (int n = 0; n < NS; ++n) he[n] = hb[n];
    float S = Sbuf[(bk * NCH + ch) * DN + d];
#pragma unroll
    for (int n = 0; n < NS; ++n) hb[n] = h[n];      // write h_init for this chunk
    float sl2 = S * L2E;
#pragma unroll
    for (int n = 0; n < NS; ++n)
      h[n] = fmaf(fast_exp2(sl2 * a[n]), h[n], he[n]);
  }
}

// ---------------- pass C: full scan from h_init, produce y -----------------------
// KSEL=1 launched first (plain store), KSEL=0 second (read-add-write). k=0 also
// adds (Ds0+Ds1)*u (both directions share the same u at the same output position).
template <int KSEL, bool ACC>
__global__ __launch_bounds__(64) void scan_passC(
    const float* __restrict__ x,
    const float* __restrict__ proj,
    const float* __restrict__ dtw_g,
    const float* __restrict__ dtb_g,
    const float* __restrict__ A2,
    const float* __restrict__ hinit,
    const float* __restrict__ Ds,       // [3840]
    float* __restrict__ y)              // [B*L][1920]
{
  int lane = threadIdx.x;
  int d = blockIdx.x * 64 + lane;
  int b = blockIdx.y;
  const int k = KSEL;
  int bk = b * 2 + k;
  int ch = blockIdx.z;
  int kd = k * DN + d;

  float a[NS], w[RR];
  const float* ap = A2 + kd * NS;
#pragma unroll
  for (int n = 0; n < NS; ++n) a[n] = ap[n];
  const float* wp = dtw_g + kd * RR;
#pragma unroll
  for (int r = 0; r < RR; ++r) w[r] = wp[r];
  float bias = dtb_g[kd];

  float dsum = 0.0f;
  if (KSEL == 0) dsum = Ds[d] + Ds[DN + d];

  int c = d / HJ, hh = d - c * HJ;
  const float* ub = x + (size_t)(b * DI + c) * LL * HJ + hh;

  const float* hb = hinit + ((size_t)(bk * NCH + ch) * DN + d) * NS;
  float h[NS];
#pragma unroll
  for (int n = 0; n < NS; ++n) h[n] = hb[n];

  int s0 = ch * CH;
  for (int s = s0; s < s0 + CH; ++s) {
    int m = k ? (LL - 1 - s) : s;
    const float* pp = proj + (size_t)(b * LL + m) * KC + k * 44;
    float dr = bias;
#pragma unroll
    for (int r = 0; r < RR; ++r) dr = fmaf(pp[r], w[r], dr);
    float delta = softplusf(dr);
    float u = ub[m * HJ];
    float du = delta * u;
    float dl2 = delta * L2E;
    float yv = dsum * u;
#pragma unroll
    for (int n = 0; n < NS; ++n) {
      float dA = fast_exp2(dl2 * a[n]);
      h[n] = fmaf(dA, h[n], du * pp[12 + n]);
      yv = fmaf(h[n], pp[28 + n], yv);
    }
    size_t yi = (size_t)(b * LL + m) * DN + d;
    if (ACC) y[yi] += yv;
    else     y[yi] = yv;
  }
}

// ---------------- LayerNorm epilogue: per (b,m), 5 groups of 384 ------------------
// block = 320 threads = 5 waves; wave w handles joint h=w.
__global__ __launch_bounds__(320) void ln_kernel(
    const float* __restrict__ y,        // [B*L][1920], d = c*5+h
    const float* __restrict__ lnw,      // [384]
    const float* __restrict__ lnb,      // [384]
    float* __restrict__ out)            // [B][L][5][384]
{
  __shared__ float yb[DN];
  int bm = blockIdx.x;
  const float* yr = y + (size_t)bm * DN;
  for (int i = threadIdx.x; i < DN; i += 320) yb[i] = yr[i];
  __syncthreads();
  int wave = threadIdx.x >> 6;
  int lane = threadIdx.x & 63;
  float v[6], sum = 0.0f, ss = 0.0f;
#pragma unroll
  for (int q = 0; q < 6; ++q) {
    int cc = lane + q * 64;
    float t = yb[cc * HJ + wave];
    v[q] = t;
    sum += t;
    ss = fmaf(t, t, ss);
  }
#pragma unroll
  for (int off = 32; off >= 1; off >>= 1) {
    sum += __shfl_xor(sum, off);
    ss  += __shfl_xor(ss, off);
  }
  float mu = sum * (1.0f / DI);
  float var = ss * (1.0f / DI) - mu * mu;
  float rs = rsqrtf(var + 1e-5f);
  float* orow = out + ((size_t)bm * HJ + wave) * DI;
#pragma unroll
  for (int q = 0; q < 6; ++q) {
    int cc = lane + q * 64;
    orow[cc] = fmaf((v[q] - mu) * rs, lnw[cc], lnb[cc]);
  }
}

// ---------------- launch ----------------------------------------------------------
extern "C" void kernel_launch(void* const* d_in, const int* in_sizes, int n_in,
                              void* d_out, int out_size, void* d_ws, size_t ws_size,
                              hipStream_t stream) {
  const float* x      = (const float*)d_in[0];
  const float* W      = (const float*)d_in[1];
  const float* dtw    = (const float*)d_in[2];
  const float* dtb    = (const float*)d_in[3];
  const float* A_logs = (const float*)d_in[4];
  const float* Ds     = (const float*)d_in[5];
  const float* lnw    = (const float*)d_in[6];
  const float* lnb    = (const float*)d_in[7];
  float* out = (float*)d_out;
  float* ws  = (float*)d_ws;

  // workspace layout (floats); total ~20.86M floats = 83.5 MB
  float* Wt   = ws;                       // 168960
  float* A2   = ws + 168960;              // 61440
  float* proj = ws + 230400;              // 720896
  float* hbuf = ws + 951296;              // 3932160
  float* Sbuf = ws + 4883456;             // 245760
  float* ybuf = ws + 5129216;             // 15728640  -> end 20857856

  hipMemsetAsync(proj, 0, (size_t)(BB * LL * KC) * sizeof(float), stream);
  prep_kernel<<<128, 256, 0, stream>>>(W, A_logs, Wt, A2);
  proj_kernel<<<dim3(128, 4), dim3(64, 4), 0, stream>>>(x, Wt, proj);
  scan_passA<<<dim3(30, 8, NCH), 64, 0, stream>>>(x, proj, dtw, dtb, A2, hbuf, Sbuf);
  scan_passB<<<60, 256, 0, stream>>>(A2, hbuf, Sbuf);
  scan_passC<1, false><<<dim3(30, 4, NCH), 64, 0, stream>>>(x, proj, dtw, dtb, A2, hbuf, Ds, ybuf);
  scan_passC<0, true ><<<dim3(30, 4, NCH), 64, 0, stream>>>(x, proj, dtw, dtb, A2, hbuf, Ds, ybuf);
  ln_kernel<<<BB * LL, 320, 0, stream>>>(ybuf, lnw, lnb, out);
}

// Round 2
// 544.698 us; speedup vs baseline: 1.3519x; 1.3519x over previous
//
#include <hip/hip_runtime.h>
#include <math.h>

// Problem constants
#define BB 4
#define LL 2048
#define DN 1920          // d_inner * joints
#define HJ 5             // joints
#define DI 384           // d_inner
#define RR 12            // dt_rank
#define NS 16            // n_state
#define KC 88            // K_GROUP * (R + 2N) = 2*44
#define NCH 16           // chunks
#define CH 128           // chunk length (L / NCH)

#define L2E 1.44269504088896f
#define LN2 0.69314718055995f

__device__ __forceinline__ float fast_exp2(float x) {
#if __has_builtin(__builtin_amdgcn_exp2f)
  return __builtin_amdgcn_exp2f(x);
#else
  return exp2f(x);
#endif
}
__device__ __forceinline__ float fast_log2(float x) {
#if __has_builtin(__builtin_amdgcn_logf)
  return __builtin_amdgcn_logf(x);   // v_log_f32 computes log2(x)
#else
  return log2f(x);
#endif
}
__device__ __forceinline__ float softplusf(float x) {
  float t = fast_exp2(x * L2E);
  float sp = LN2 * fast_log2(1.0f + t);
  return (x > 20.0f) ? x : sp;
}

// ---------------- prep: transpose x_proj_weight to [d][88], A2 = -exp(A_logs) ----
__global__ __launch_bounds__(256) void prep_kernel(
    const float* __restrict__ W,        // [2][44][1920]
    const float* __restrict__ A_logs,   // [3840][16]
    float* __restrict__ Wt,             // [1920][88]
    float* __restrict__ A2)             // [3840][16]
{
  int i = blockIdx.x * blockDim.x + threadIdx.x;
  int stride = gridDim.x * blockDim.x;
  for (int idx = i; idx < DN * KC; idx += stride) {
    int d = idx / KC;
    int j = idx - d * KC;               // j = k*44 + c
    Wt[idx] = W[j * DN + d];
  }
  for (int idx = i; idx < 2 * DN * NS; idx += stride) {
    A2[idx] = -expf(A_logs[idx]);
  }
}

// ---------------- projection: skinny GEMM C[mg][j] = sum_d X[mg,d] Wt[d][j] -----
// grid (128 m-tiles, 2 K-halves), block (64,4). LDS-staged X, s_load weights.
// Each thread: m = tx (64-tile), 22 outputs (ty quarter). K-half = 192 cdi's.
__global__ __launch_bounds__(256) void proj_kernel(
    const float* __restrict__ x,        // [B][384][2048][5]
    const float* __restrict__ Wt,       // [1920][88]
    float* __restrict__ proj)           // [B*L][88]  (pre-zeroed; atomic combine)
{
  __shared__ float xs[16 * 64 * HJ];    // c-chunk 16 x 64 m x 5 h = 20 KB
  int tx = threadIdx.x;                                   // 0..63 -> m
  int ty = __builtin_amdgcn_readfirstlane(threadIdx.y);   // 0..3, wave-uniform
  int t = threadIdx.y * 64 + tx;                          // 0..255
  int mt = blockIdx.x * 64;             // global position tile
  int b = mt >> 11;
  int m0 = mt & (LL - 1);
  int cdi0 = blockIdx.y * 192;          // K-half over d_inner channels

  float acc[22];
#pragma unroll
  for (int j = 0; j < 22; ++j) acc[j] = 0.0f;

  for (int cc = 0; cc < 192; cc += 16) {
    __syncthreads();
    // stage 16 rows; row cl = 320 contiguous floats at x[((b*384+c)*2048+m0)*5]
#pragma unroll
    for (int q = 0; q < 5; ++q) {
      int idx = q * 256 + t;            // float4 index 0..1279
      int cl = idx / 80;                // 80 float4 per row
      int off = idx - cl * 80;
      const float4* src = (const float4*)(x +
          ((size_t)(b * DI + cdi0 + cc + cl) * LL + m0) * HJ) + off;
      ((float4*)xs)[idx] = *src;
    }
    __syncthreads();
    // compute 80 d's (16 cdi x 5 h); weight pointer is wave-uniform -> s_load
    for (int cl = 0; cl < 16; ++cl) {
#pragma unroll
      for (int h = 0; h < HJ; ++h) {
        float xv = xs[cl * 320 + tx * HJ + h];
        const float* w = Wt + (size_t)(cdi0 + cc + cl) * HJ * KC + h * KC + ty * 22;
#pragma unroll
        for (int j = 0; j < 22; ++j) acc[j] = fmaf(w[j], xv, acc[j]);
      }
    }
  }
  float* pr = proj + (size_t)(mt + tx) * KC + ty * 22;
#pragma unroll
  for (int j = 0; j < 22; ++j) atomicAdd(pr + j, acc[j]);
}

// ---------------- pass A: per-chunk h_end (from h0=0) and S = sum(delta) --------
__global__ __launch_bounds__(64) void scan_passA(
    const float* __restrict__ x,
    const float* __restrict__ proj,     // [B*L][88]
    const float* __restrict__ dtw_g,    // [2][1920][12]
    const float* __restrict__ dtb_g,    // [2][1920]
    const float* __restrict__ A2,       // [2*1920][16]
    float* __restrict__ hend,           // [8][16][1920][16]
    float* __restrict__ Sout)           // [8][16][1920]
{
  int lane = threadIdx.x;
  int d = blockIdx.x * 64 + lane;
  int bk = blockIdx.y;
  int b = bk >> 1, k = bk & 1;
  int ch = blockIdx.z;
  int kd = k * DN + d;

  float a[NS], w[RR];
  const float* ap = A2 + kd * NS;
#pragma unroll
  for (int n = 0; n < NS; ++n) a[n] = ap[n];
  const float* wp = dtw_g + kd * RR;
#pragma unroll
  for (int r = 0; r < RR; ++r) w[r] = wp[r];
  float bias = dtb_g[kd];

  int c = d / HJ, hh = d - c * HJ;
  const float* ub = x + (size_t)(b * DI + c) * LL * HJ + hh;

  float h[NS];
#pragma unroll
  for (int n = 0; n < NS; ++n) h[n] = 0.0f;
  float S = 0.0f;

  int s0 = ch * CH;
  for (int s = s0; s < s0 + CH; ++s) {
    int m = k ? (LL - 1 - s) : s;
    // wave-uniform position -> force scalar loads of the 44 proj values
    int mu = __builtin_amdgcn_readfirstlane(b * LL + m);
    const float* pp = proj + (size_t)mu * KC + k * 44;
    float dr = bias;
#pragma unroll
    for (int r = 0; r < RR; ++r) dr = fmaf(pp[r], w[r], dr);
    float delta = softplusf(dr);
    float u = ub[m * HJ];
    float du = delta * u;
    float dl2 = delta * L2E;
#pragma unroll
    for (int n = 0; n < NS; ++n) {
      float dA = fast_exp2(dl2 * a[n]);
      h[n] = fmaf(dA, h[n], du * pp[12 + n]);
    }
    S += delta;
  }
  float* hb = hend + ((size_t)(bk * NCH + ch) * DN + d) * NS;
#pragma unroll
  for (int n = 0; n < NS; ++n) hb[n] = h[n];
  Sout[(bk * NCH + ch) * DN + d] = S;
}

// ---------------- pass B: sequential chunk combine; hbuf becomes h_init ---------
__global__ __launch_bounds__(256) void scan_passB(
    const float* __restrict__ A2,
    float* __restrict__ hbuf,           // in: h_end, out: h_init
    const float* __restrict__ Sbuf)
{
  int idx = blockIdx.x * 256 + threadIdx.x;   // 0..15359
  if (idx >= 8 * DN) return;
  int bk = idx / DN, d = idx - bk * DN;
  int k = bk & 1;
  const float* ap = A2 + (k * DN + d) * NS;
  float a[NS];
#pragma unroll
  for (int n = 0; n < NS; ++n) a[n] = ap[n];
  float h[NS];
#pragma unroll
  for (int n = 0; n < NS; ++n) h[n] = 0.0f;
  for (int ch = 0; ch < NCH; ++ch) {
    float* hb = hbuf + ((size_t)(bk * NCH + ch) * DN + d) * NS;
    float he[NS];
#pragma unroll
    for (int n = 0; n < NS; ++n) he[n] = hb[n];
    float S = Sbuf[(bk * NCH + ch) * DN + d];
#pragma unroll
    for (int n = 0; n < NS; ++n) hb[n] = h[n];      // write h_init for this chunk
    float sl2 = S * L2E;
#pragma unroll
    for (int n = 0; n < NS; ++n)
      h[n] = fmaf(fast_exp2(sl2 * a[n]), h[n], he[n]);
  }
}

// ---------------- pass C: full scan from h_init, produce y -----------------------
template <int KSEL, bool ACC>
__global__ __launch_bounds__(64) void scan_passC(
    const float* __restrict__ x,
    const float* __restrict__ proj,
    const float* __restrict__ dtw_g,
    const float* __restrict__ dtb_g,
    const float* __restrict__ A2,
    const float* __restrict__ hinit,
    const float* __restrict__ Ds,       // [3840]
    float* __restrict__ y)              // [B*L][1920]
{
  int lane = threadIdx.x;
  int d = blockIdx.x * 64 + lane;
  int b = blockIdx.y;
  const int k = KSEL;
  int bk = b * 2 + k;
  int ch = blockIdx.z;
  int kd = k * DN + d;

  float a[NS], w[RR];
  const float* ap = A2 + kd * NS;
#pragma unroll
  for (int n = 0; n < NS; ++n) a[n] = ap[n];
  const float* wp = dtw_g + kd * RR;
#pragma unroll
  for (int r = 0; r < RR; ++r) w[r] = wp[r];
  float bias = dtb_g[kd];

  float dsum = 0.0f;
  if (KSEL == 0) dsum = Ds[d] + Ds[DN + d];

  int c = d / HJ, hh = d - c * HJ;
  const float* ub = x + (size_t)(b * DI + c) * LL * HJ + hh;

  const float* hb = hinit + ((size_t)(bk * NCH + ch) * DN + d) * NS;
  float h[NS];
#pragma unroll
  for (int n = 0; n < NS; ++n) h[n] = hb[n];

  int s0 = ch * CH;
  for (int s = s0; s < s0 + CH; ++s) {
    int m = k ? (LL - 1 - s) : s;
    int mu = __builtin_amdgcn_readfirstlane(b * LL + m);
    const float* pp = proj + (size_t)mu * KC + k * 44;
    float dr = bias;
#pragma unroll
    for (int r = 0; r < RR; ++r) dr = fmaf(pp[r], w[r], dr);
    float delta = softplusf(dr);
    float u = ub[m * HJ];
    float du = delta * u;
    float dl2 = delta * L2E;
    float yv = dsum * u;
#pragma unroll
    for (int n = 0; n < NS; ++n) {
      float dA = fast_exp2(dl2 * a[n]);
      h[n] = fmaf(dA, h[n], du * pp[12 + n]);
      yv = fmaf(h[n], pp[28 + n], yv);
    }
    size_t yi = (size_t)(b * LL + m) * DN + d;
    if (ACC) y[yi] += yv;
    else     y[yi] = yv;
  }
}

// ---------------- LayerNorm epilogue: per (b,m), 5 groups of 384 ------------------
__global__ __launch_bounds__(320) void ln_kernel(
    const float* __restrict__ y,        // [B*L][1920], d = c*5+h
    const float* __restrict__ lnw,      // [384]
    const float* __restrict__ lnb,      // [384]
    float* __restrict__ out)            // [B][L][5][384]
{
  __shared__ float yb[DN];
  int bm = blockIdx.x;
  const float* yr = y + (size_t)bm * DN;
  for (int i = threadIdx.x; i < DN; i += 320) yb[i] = yr[i];
  __syncthreads();
  int wave = threadIdx.x >> 6;
  int lane = threadIdx.x & 63;
  float v[6], sum = 0.0f, ss = 0.0f;
#pragma unroll
  for (int q = 0; q < 6; ++q) {
    int cc = lane + q * 64;
    float t = yb[cc * HJ + wave];
    v[q] = t;
    sum += t;
    ss = fmaf(t, t, ss);
  }
#pragma unroll
  for (int off = 32; off >= 1; off >>= 1) {
    sum += __shfl_xor(sum, off);
    ss  += __shfl_xor(ss, off);
  }
  float mu = sum * (1.0f / DI);
  float var = ss * (1.0f / DI) - mu * mu;
  float rs = rsqrtf(var + 1e-5f);
  float* orow = out + ((size_t)bm * HJ + wave) * DI;
#pragma unroll
  for (int q = 0; q < 6; ++q) {
    int cc = lane + q * 64;
    orow[cc] = fmaf((v[q] - mu) * rs, lnw[cc], lnb[cc]);
  }
}

// ---------------- launch ----------------------------------------------------------
extern "C" void kernel_launch(void* const* d_in, const int* in_sizes, int n_in,
                              void* d_out, int out_size, void* d_ws, size_t ws_size,
                              hipStream_t stream) {
  const float* x      = (const float*)d_in[0];
  const float* W      = (const float*)d_in[1];
  const float* dtw    = (const float*)d_in[2];
  const float* dtb    = (const float*)d_in[3];
  const float* A_logs = (const float*)d_in[4];
  const float* Ds     = (const float*)d_in[5];
  const float* lnw    = (const float*)d_in[6];
  const float* lnb    = (const float*)d_in[7];
  float* out = (float*)d_out;
  float* ws  = (float*)d_ws;

  // workspace layout (floats); total ~20.86M floats = 83.5 MB
  float* Wt   = ws;                       // 168960
  float* A2   = ws + 168960;              // 61440
  float* proj = ws + 230400;              // 720896
  float* hbuf = ws + 951296;              // 3932160
  float* Sbuf = ws + 4883456;             // 245760
  float* ybuf = ws + 5129216;             // 15728640  -> end 20857856

  hipMemsetAsync(proj, 0, (size_t)(BB * LL * KC) * sizeof(float), stream);
  prep_kernel<<<128, 256, 0, stream>>>(W, A_logs, Wt, A2);
  proj_kernel<<<dim3(128, 2), dim3(64, 4), 0, stream>>>(x, Wt, proj);
  scan_passA<<<dim3(30, 8, NCH), 64, 0, stream>>>(x, proj, dtw, dtb, A2, hbuf, Sbuf);
  scan_passB<<<60, 256, 0, stream>>>(A2, hbuf, Sbuf);
  scan_passC<1, false><<<dim3(30, 4, NCH), 64, 0, stream>>>(x, proj, dtw, dtb, A2, hbuf, Ds, ybuf);
  scan_passC<0, true ><<<dim3(30, 4, NCH), 64, 0, stream>>>(x, proj, dtw, dtb, A2, hbuf, Ds, ybuf);
  ln_kernel<<<BB * LL, 320, 0, stream>>>(ybuf, lnw, lnb, out);
}